// Round 1
// baseline (37.759 us; speedup 1.0000x reference)
//
#include <hip/hip_runtime.h>

// LengthRegulator: out[b,c,t] = x[b,c,idx(b,t)] where idx(b,t) is the unique
// input token i whose segment owns output frame t (path is a 0/1 disjoint
// segment mask, so bmm(x, path) == gather). Exact vs reference.

#define LR_B 32
#define LR_C 256
#define LR_TIN 256
#define LR_TOUT 2048

// Kernel 1: idx[b,t] = argmax_i path[b,i,t] (exactly one i has path==1).
// grid (T_OUT/256, B), block 256. Loads are coalesced across t.
__global__ __launch_bounds__(256) void lr_idx_kernel(const float* __restrict__ path,
                                                     int* __restrict__ idx) {
    const int t = blockIdx.x * 256 + threadIdx.x;
    const int b = blockIdx.y;
    const float* p = path + (size_t)b * LR_TIN * LR_TOUT + t;
    int id = 0;
#pragma unroll 8
    for (int i = 0; i < LR_TIN; ++i) {
        float v = p[(size_t)i * LR_TOUT];
        if (v != 0.0f) id = i;
    }
    idx[b * LR_TOUT + t] = id;
}

// Kernel 2: out[b,c,t] = x[b,c,idx[b,t]], 4 t's per thread (float4 store).
__global__ __launch_bounds__(256) void lr_gather_kernel(const float* __restrict__ x,
                                                        const int* __restrict__ idx,
                                                        float* __restrict__ out) {
    const int lin = blockIdx.x * 256 + threadIdx.x;
    const int T4 = LR_TOUT / 4;
    const int t4 = (lin % T4) * 4;
    const int c  = (lin / T4) % LR_C;
    const int b  = lin / (T4 * LR_C);
    const int4 iv = *reinterpret_cast<const int4*>(idx + b * LR_TOUT + t4);
    const float* xrow = x + ((size_t)b * LR_C + c) * LR_TIN;
    float4 o;
    o.x = xrow[iv.x];
    o.y = xrow[iv.y];
    o.z = xrow[iv.z];
    o.w = xrow[iv.w];
    *reinterpret_cast<float4*>(out + ((size_t)b * LR_C + c) * LR_TOUT + t4) = o;
}

// Fallback (no workspace needed): fused per-(b, t-tile) kernel.
__global__ __launch_bounds__(256) void lr_fused_kernel(const float* __restrict__ x,
                                                       const float* __restrict__ path,
                                                       float* __restrict__ out) {
    const int t = blockIdx.x * 256 + threadIdx.x;
    const int b = blockIdx.y;
    const float* p = path + (size_t)b * LR_TIN * LR_TOUT + t;
    int id = 0;
#pragma unroll 8
    for (int i = 0; i < LR_TIN; ++i) {
        if (p[(size_t)i * LR_TOUT] != 0.0f) id = i;
    }
    const float* xb = x + (size_t)b * LR_C * LR_TIN;
    float* ob = out + (size_t)b * LR_C * LR_TOUT + t;
#pragma unroll 4
    for (int c = 0; c < LR_C; ++c) {
        ob[(size_t)c * LR_TOUT] = xb[(size_t)c * LR_TIN + id];
    }
}

extern "C" void kernel_launch(void* const* d_in, const int* in_sizes, int n_in,
                              void* d_out, int out_size, void* d_ws, size_t ws_size,
                              hipStream_t stream) {
    const float* x    = (const float*)d_in[0];   // [B, C, T_IN] fp32
    const float* path = (const float*)d_in[1];   // [B, T_IN, T_OUT] fp32
    float* out = (float*)d_out;                  // [B, C, T_OUT] fp32

    const size_t idx_bytes = (size_t)LR_B * LR_TOUT * sizeof(int);
    if (ws_size >= idx_bytes) {
        int* idx = (int*)d_ws;
        lr_idx_kernel<<<dim3(LR_TOUT / 256, LR_B), 256, 0, stream>>>(path, idx);
        const int total_threads = LR_B * LR_C * (LR_TOUT / 4);
        lr_gather_kernel<<<total_threads / 256, 256, 0, stream>>>(x, idx, out);
    } else {
        lr_fused_kernel<<<dim3(LR_TOUT / 256, LR_B), 256, 0, stream>>>(x, path, out);
    }
}